// Round 6
// baseline (100.878 us; speedup 1.0000x reference)
//
#include <hip/hip_runtime.h>

typedef unsigned short u16;
typedef unsigned int u32;
typedef __attribute__((ext_vector_type(8))) short bfx8;
typedef __attribute__((ext_vector_type(4))) float fx4;
typedef __attribute__((ext_vector_type(4))) u32 ux4;
typedef __attribute__((ext_vector_type(2))) u32 ux2;

__device__ inline u32 f2bf(float v) {
  u32 u = __builtin_bit_cast(u32, v);
  u = (u + 0x7fffu + ((u >> 16) & 1u)) >> 16; // RNE
  return u;
}

// ---- zero the 32 per-(b,hh) arrival counters (ws is poisoned every iter) ----
__global__ __launch_bounds__(64) void eq_init(u32* __restrict__ ctr) {
  if (threadIdx.x < 32) ctr[threadIdx.x] = 0u;
}

// ---------------- fused MFMA kernel (split-K=16, last-block reduction) ----------
// Grid: 512 blocks = 16 ich * 2 hh * 16 b (2 i each, 128-h half each).
// Core identical to the verified round-5 kernel (same partials, same layout).
// New: after the partial store, t0 fences + atomicAdd ctr[b*2+hh]; the 16th
// (last) block of the group re-reads the 16 chunks (L2/L3-hot, overlapped with
// other groups' compute) and writes out = sum(c=0..15) + bias — the SAME
// summation order as the old eq_reduce, so results are bit-identical.
__global__ __launch_bounds__(512, 4) void eq_main(const float* __restrict__ xin,
                                                  const float* __restrict__ kin,
                                                  const float* __restrict__ bias,
                                                  float* __restrict__ part,
                                                  u32* __restrict__ ctr,
                                                  float* __restrict__ out) {
  __shared__ __align__(16) char smem[74752];
  u16* As = (u16*)smem;                    // [2 i][64 f][256 s] bf16, swizzled (64 KB)
  u32* P4 = (u32*)(smem + 65536);          // [2 i][16 r][2 par][8 u0][4] quads (8 KB)
  u16* xraw = (u16*)(smem + 73728);        // [2 i][256 s] bf16 bits (1 KB)
  float* red = (float*)smem;               // epilogue alias: [4 wq][32 hloc][68] (34.8 KB)
  __shared__ int lastFlag;

  const int b = blockIdx.x & 15;
  const int hh = (blockIdx.x >> 4) & 1;
  const int ich = blockIdx.x >> 5;
  const int t = threadIdx.x;

  // ---- stage x (2 rows of 256 fp32 -> bf16) ----
  if (t < 128) {
    int iLoc = t >> 6, s4 = (t & 63) << 2;
    fx4 v = *(const fx4*)(xin + ((b << 5) + (ich << 1) + iLoc) * 256 + s4);
    ux2 p;
    p[0] = f2bf(v[0]) | (f2bf(v[1]) << 16);
    p[1] = f2bf(v[2]) | (f2bf(v[3]) << 16);
    *(ux2*)(xraw + iLoc * 256 + s4) = p;
  }

  // ---- stage kernel slice: 2 i * 64 f * 256 s fp32 -> bf16 LDS, swizzled ----
#pragma unroll
  for (int it = 0; it < 8; ++it) {
    int slot = it * 512 + t;            // 0..4095
    int iLoc = slot >> 11;
    int f = (slot >> 5) & 63;
    int c = slot & 31;
    int cs = c ^ (f & 31);
    const float* src = kin + f * 8192 + ((ich << 1) + iLoc) * 256 + (cs << 3);
    fx4 v0 = *(const fx4*)src;
    fx4 v1 = *(const fx4*)(src + 4);
    ux4 p;
    p[0] = f2bf(v0[0]) | (f2bf(v0[1]) << 16);
    p[1] = f2bf(v0[2]) | (f2bf(v0[3]) << 16);
    p[2] = f2bf(v1[0]) | (f2bf(v1[1]) << 16);
    p[3] = f2bf(v1[2]) | (f2bf(v1[3]) << 16);
    *(ux4*)(As + slot * 8) = p;
  }
  __syncthreads();

  // ---- build P4: pre-grouped rotation quads ----
  {
    int iLoc = t >> 8, e = t & 255;
    int r = e >> 4, par = (e >> 3) & 1, u0 = e & 7;
    const u16* xr = xraw + iLoc * 256 + (r << 4);
    ux4 q;
#pragma unroll
    for (int j = 0; j < 4; ++j) {
      int u = u0 + j;
      int c0 = (32 - 2 * u) & 15;
      u32 lo = xr[(c0 - par) & 15];
      u32 hi = xr[(c0 - par - 1) & 15];
      q[j] = lo | (hi << 16);
    }
    *(ux4*)(P4 + (t << 2)) = q;
  }
  __syncthreads();

  const int lane = t & 63;
  const int w = t >> 6;
  const int iLoc = w >> 2;
  const int wq = w & 3;
  const int n = lane & 15;
  const int quad = lane >> 4;
  const int s2_0 = (quad & 1) << 3;
  const int par = n & 1;
  const int u0 = ((s2_0 - n - par) & 15) >> 1;
  const int Pb4 = (iLoc << 10) + (par << 5) + (u0 << 2);
  const int s1q = quad >> 1;
  const u16* Aw = As + (iLoc << 14);
  const int Tbase = (hh << 3) + (wq << 1);

  fx4 acc[4][2];
#pragma unroll
  for (int a = 0; a < 4; ++a)
#pragma unroll
    for (int c = 0; c < 2; ++c) acc[a][c] = (fx4){0.f, 0.f, 0.f, 0.f};

#pragma unroll
  for (int kstep = 0; kstep < 8; ++kstep) {
    bfx8 af[4];
#pragma unroll
    for (int ft = 0; ft < 4; ++ft) {
      int f = (ft << 4) + n;
      int ch = ((kstep << 2) + quad) ^ (f & 31);
      af[ft] = *(const bfx8*)(Aw + f * 256 + ch * 8);
    }
    const int s1 = (kstep << 1) + s1q;
    bfx8 bfr[2];
#pragma unroll
    for (int ht = 0; ht < 2; ++ht) {
      int r = (Tbase + ht - s1) & 15;
      bfr[ht] = __builtin_bit_cast(bfx8, *(const ux4*)(P4 + (r << 6) + Pb4));
    }
#pragma unroll
    for (int ft = 0; ft < 4; ++ft)
#pragma unroll
      for (int ht = 0; ht < 2; ++ht)
        acc[ft][ht] =
            __builtin_amdgcn_mfma_f32_16x16x32_bf16(af[ft], bfr[ht], acc[ft][ht], 0, 0, 0);
  }

  // all waves done reading As/P4 before red (aliased) is written
  __syncthreads();

  // ---- cross-wave (i) reduction: upper waves write, lower add + store ----
  if (w >= 4) {
#pragma unroll
    for (int ft = 0; ft < 4; ++ft)
#pragma unroll
      for (int ht = 0; ht < 2; ++ht) {
        float* pr = &red[wq * 2176 + (ht * 16 + n) * 68 + (ft << 4) + (quad << 2)];
        *(fx4*)pr = acc[ft][ht];
      }
  }
  __syncthreads();
  if (w < 4) {
    float* pw = part + (((ich << 4) + b) << 14);
#pragma unroll
    for (int ft = 0; ft < 4; ++ft)
#pragma unroll
      for (int ht = 0; ht < 2; ++ht) {
        const float* pr = &red[wq * 2176 + (ht * 16 + n) * 68 + (ft << 4) + (quad << 2)];
        fx4 vv = *(const fx4*)pr;
        acc[ft][ht] = acc[ft][ht] + vv;
        int h = (hh << 7) + (wq << 5) + (ht << 4) + n;
#pragma unroll
        for (int reg = 0; reg < 4; ++reg) {
          int f = (ft << 4) + (quad << 2) + reg;
          pw[f * 256 + h] = acc[ft][ht][reg];
        }
      }
  }

  // ---- last-block split-K reduction (no spin: only the 16th arrival works) ----
  __syncthreads();   // every wave's partial stores drained (waitcnt before barrier)
  if (t == 0) {
    __threadfence();                                   // release: L2 writeback
    u32 old = atomicAdd(&ctr[(b << 1) + hh], 1u);
    lastFlag = (old == 15u);
  }
  __syncthreads();
  if (lastFlag) {
    __threadfence();                                   // acquire: invalidate stale L2
    const int base = (hh << 7);
#pragma unroll
    for (int j = 0; j < 4; ++j) {
      int id = j * 512 + t;          // 0..2047 fx4 elements = 64 f * 32 (128h/4)
      int f = id >> 5;
      int hl4 = (id & 31) << 2;
      fx4 s = {0.f, 0.f, 0.f, 0.f};
#pragma unroll
      for (int c = 0; c < 16; ++c)
        s = s + *(const fx4*)(part + (((c << 4) + b) << 14) + (f << 8) + base + hl4);
      float bv = bias[f];
      s = s + (fx4){bv, bv, bv, bv};
      *(fx4*)(out + (b << 14) + (f << 8) + base + hl4) = s;
    }
  }
}

extern "C" void kernel_launch(void* const* d_in, const int* in_sizes, int n_in,
                              void* d_out, int out_size, void* d_ws, size_t ws_size,
                              hipStream_t stream) {
  (void)in_sizes; (void)n_in; (void)out_size; (void)ws_size;
  const float* x = (const float*)d_in[0];
  const float* k = (const float*)d_in[1];
  const float* bias = (const float*)d_in[2];
  // d_in[3] (product_table) unused: translation-group indices computed analytically.
  float* part = (float*)d_ws;            // 16 chunks * 16 b * 16384 * 4 B = 16.8 MB
  u32* ctr = (u32*)((char*)d_ws + 16u * 16u * 16384u * 4u);  // 32 counters after partials
  float* out = (float*)d_out;

  eq_init<<<1, 64, 0, stream>>>(ctr);
  eq_main<<<512, 512, 0, stream>>>(x, k, bias, part, ctr, out);
}

// Round 7
// 80.665 us; speedup vs baseline: 1.2506x; 1.2506x over previous
//
#include <hip/hip_runtime.h>

typedef unsigned short u16;
typedef unsigned int u32;
typedef __attribute__((ext_vector_type(8))) short bfx8;
typedef __attribute__((ext_vector_type(4))) float fx4;
typedef __attribute__((ext_vector_type(4))) u32 ux4;
typedef __attribute__((ext_vector_type(2))) u32 ux2;

__device__ inline u32 f2bf(float v) {
  u32 u = __builtin_bit_cast(u32, v);
  u = (u + 0x7fffu + ((u >> 16) & 1u)) >> 16; // RNE
  return u;
}

// ---------------- main MFMA kernel (split-K=4, in-block ich loop) ------------
// Grid: 256 blocks = 16 b * 4 ichg * 4 hq. Block: 512 thr = 8 waves.
// Block loops ic=0..3 over ich = ichg*4+ic (2 i each), re-staging As/P4 per ic
// and ACCUMULATING acc across the loop (in-register split-K fusion; no fences,
// no atomics, all cross-i communication in-block).
// Wave w: iLoc = w>>2, wq = w&3 -> h-tile T = hq*4 + wq ([64 f][16 h]), 8 ksteps.
// Epilogue (verified round-0/5 pattern): waves 4..7 dump acc to LDS; waves 0..3
// add -> one partial per (ichg, b): part[(ichg*16+b)*16384 + f*256 + h].
// part = 4 chunks * 1 MB = 4.2 MB (was 16.8).
// LDS: As 64K + P4 8K + xraw 4K = 76 KB -> 2 blocks/CU; red (17.4K) aliases As.
__global__ __launch_bounds__(512, 4) void eq_main(const float* __restrict__ xin,
                                                  const float* __restrict__ kin,
                                                  float* __restrict__ part) {
  __shared__ __align__(16) char smem[77824];
  u16* As = (u16*)smem;               // [2 iLoc][64 f][256 s] bf16, swizzled (64 KB)
  u32* P4 = (u32*)(smem + 65536);     // [2 iLoc][16 r][2 par][8 u0][4] quads (8 KB)
  u16* xraw = (u16*)(smem + 73728);   // [8 i][256 s] bf16 bits (4 KB)
  float* red = (float*)smem;          // epilogue alias: [4 wq][16 n][68] (17.4 KB)

  const int b = blockIdx.x & 15;
  const int ichg = (blockIdx.x >> 4) & 3;
  const int hq = blockIdx.x >> 6;
  const int t = threadIdx.x;

  // ---- stage x: this block's 8 i-rows of 256 fp32 -> bf16 (once) ----
  {
    int iLoc = t >> 6, s4 = (t & 63) << 2;
    fx4 v = *(const fx4*)(xin + ((b << 5) + (ichg << 3) + iLoc) * 256 + s4);
    ux2 p;
    p[0] = f2bf(v[0]) | (f2bf(v[1]) << 16);
    p[1] = f2bf(v[2]) | (f2bf(v[3]) << 16);
    *(ux2*)(xraw + iLoc * 256 + s4) = p;
  }
  __syncthreads();

  const int lane = t & 63;
  const int w = t >> 6;
  const int iLoc = w >> 2;
  const int wq = w & 3;
  const int n = lane & 15;
  const int quad = lane >> 4;
  const int s2_0 = (quad & 1) << 3;
  const int par = n & 1;
  const int u0 = ((s2_0 - n - par) & 15) >> 1;
  const int Pb4 = (iLoc << 10) + (par << 5) + (u0 << 2);
  const int s1q = quad >> 1;
  const u16* Aw = As + (iLoc << 14);
  const int T = (hq << 2) + wq;       // global h-tile index for this wave

  fx4 acc[4];
#pragma unroll
  for (int a = 0; a < 4; ++a) acc[a] = (fx4){0.f, 0.f, 0.f, 0.f};

  for (int ic = 0; ic < 4; ++ic) {
    // ---- stage kernel slice for ich = ichg*4+ic: 2 i * 64 f * 256 s, swizzled ----
#pragma unroll
    for (int it = 0; it < 8; ++it) {
      int slot = it * 512 + t;            // 0..4095
      int iL = slot >> 11;
      int f = (slot >> 5) & 63;
      int c = slot & 31;
      int cs = c ^ (f & 31);
      const float* src = kin + f * 8192 + (((ichg << 2) + ic) * 2 + iL) * 256 + (cs << 3);
      fx4 v0 = *(const fx4*)src;
      fx4 v1 = *(const fx4*)(src + 4);
      ux4 p;
      p[0] = f2bf(v0[0]) | (f2bf(v0[1]) << 16);
      p[1] = f2bf(v0[2]) | (f2bf(v0[3]) << 16);
      p[2] = f2bf(v1[0]) | (f2bf(v1[1]) << 16);
      p[3] = f2bf(v1[2]) | (f2bf(v1[3]) << 16);
      *(ux4*)(As + slot * 8) = p;
    }
    // ---- build P4 for this ic (reads xraw rows ic*2 + iL) ----
    {
      int iL = t >> 8, e = t & 255;
      int r = e >> 4, pr = (e >> 3) & 1, uu = e & 7;
      const u16* xr = xraw + ((ic << 1) + iL) * 256 + (r << 4);
      ux4 q;
#pragma unroll
      for (int j = 0; j < 4; ++j) {
        int u = uu + j;
        int c0 = (32 - 2 * u) & 15;
        u32 lo = xr[(c0 - pr) & 15];
        u32 hi = xr[(c0 - pr - 1) & 15];
        q[j] = lo | (hi << 16);
      }
      *(ux4*)(P4 + (t << 2)) = q;
    }
    __syncthreads();

    // ---- 8 ksteps, accumulate into acc (across ic too) ----
#pragma unroll
    for (int kstep = 0; kstep < 8; ++kstep) {
      bfx8 af[4];
#pragma unroll
      for (int ft = 0; ft < 4; ++ft) {
        int f = (ft << 4) + n;
        int ch = ((kstep << 2) + quad) ^ (f & 31);
        af[ft] = *(const bfx8*)(Aw + f * 256 + ch * 8);
      }
      const int s1 = (kstep << 1) + s1q;
      int r = (T - s1) & 15;
      bfx8 bfr = __builtin_bit_cast(bfx8, *(const ux4*)(P4 + (r << 6) + Pb4));
#pragma unroll
      for (int ft = 0; ft < 4; ++ft)
        acc[ft] = __builtin_amdgcn_mfma_f32_16x16x32_bf16(af[ft], bfr, acc[ft], 0, 0, 0);
    }
    __syncthreads();   // before next ic overwrites As/P4 (and before red alias at end)
  }

  // ---- cross-wave (i) reduction: upper waves write, lower add + store ----
  if (w >= 4) {
#pragma unroll
    for (int ft = 0; ft < 4; ++ft) {
      float* pr = &red[wq * 1088 + n * 68 + (ft << 4) + (quad << 2)];
      *(fx4*)pr = acc[ft];
    }
  }
  __syncthreads();
  if (w < 4) {
    float* pw = part + (((ichg << 4) + b) << 14);
#pragma unroll
    for (int ft = 0; ft < 4; ++ft) {
      const float* pr = &red[wq * 1088 + n * 68 + (ft << 4) + (quad << 2)];
      fx4 vv = *(const fx4*)pr;
      fx4 s = acc[ft] + vv;
      int h = (hq << 6) + (wq << 4) + n;
#pragma unroll
      for (int reg = 0; reg < 4; ++reg) {
        int f = (ft << 4) + (quad << 2) + reg;
        pw[f * 256 + h] = s[reg];
      }
    }
  }
}

// ---------------- split-K=4 reduction + bias ----------------
__global__ __launch_bounds__(256) void eq_reduce(const float* __restrict__ part,
                                                 const float* __restrict__ bias,
                                                 float* __restrict__ out) {
  int o = (blockIdx.x * 256 + threadIdx.x) * 4;
  fx4 s = {0.f, 0.f, 0.f, 0.f};
#pragma unroll
  for (int i = 0; i < 4; ++i) s = s + *(const fx4*)(part + i * 262144 + o);
  float bv = bias[(o >> 8) & 63];
  s = s + (fx4){bv, bv, bv, bv};
  *(fx4*)(out + o) = s;
}

extern "C" void kernel_launch(void* const* d_in, const int* in_sizes, int n_in,
                              void* d_out, int out_size, void* d_ws, size_t ws_size,
                              hipStream_t stream) {
  (void)in_sizes; (void)n_in; (void)out_size; (void)ws_size;
  const float* x = (const float*)d_in[0];
  const float* k = (const float*)d_in[1];
  const float* bias = (const float*)d_in[2];
  // d_in[3] (product_table) unused: translation-group indices computed analytically.
  float* part = (float*)d_ws;   // 4 chunks * 16 b * 64 f * 256 h * 4 B = 4.2 MB
  float* out = (float*)d_out;

  eq_main<<<256, 512, 0, stream>>>(x, k, part);
  eq_reduce<<<256, 256, 0, stream>>>(part, bias, out);
}

// Round 9
// 73.978 us; speedup vs baseline: 1.3636x; 1.0904x over previous
//
#include <hip/hip_runtime.h>
#include <hip/hip_bf16.h>

typedef unsigned short u16;
typedef unsigned int u32;
typedef __attribute__((ext_vector_type(8))) short bfx8;
typedef __attribute__((ext_vector_type(4))) float fx4;
typedef __attribute__((ext_vector_type(4))) u32 ux4;
typedef __attribute__((ext_vector_type(2))) u32 ux2;

// packed fp32x2 -> bf16x2 (RNE) via v_cvt_pk_bf16_f32; a -> low 16, b -> high 16
__device__ inline u32 pkbf(float a, float b) {
  __hip_bfloat162 h = __float22bfloat162_rn(float2{a, b});
  u32 r;
  __builtin_memcpy(&r, &h, 4);   // __hip_bfloat162 not trivially copyable -> no bit_cast
  return r;
}

// ---------------- main MFMA kernel (conversion fused, split-K=16) ----------------
// Grid: 256 blocks = 16 b * 16 ichunk (2 i each). Block: 512 thr = 8 waves.
// Wave w: i = ich*2 + (w>>2), h-quarter wq = w&3 -> [64 f][64 h] tile, 8 ksteps.
// Epilogue: waves 4..7 (i odd) dump acc to LDS; waves 0..3 add -> one partial
// per (ich, b): part[(ich*16+b)*16384 + f*256 + h], 16 chunks total (16.8 MB).
// (Structure identical to the measured-73.06 R3 kernel; only the fp32->bf16
// conversion changed from manual bit-RNE (~6 VALU/elem) to v_cvt_pk_bf16_f32.)
__global__ __launch_bounds__(512, 1) void eq_main(const float* __restrict__ xin,
                                                  const float* __restrict__ kin,
                                                  float* __restrict__ part) {
  __shared__ u16 As[32768];        // [2 i][64 f][256 s] bf16, 16B chunks XOR-swizzled
  __shared__ u32 P4[2048];         // [2 i][16 r][2 par][8 u0][4] pre-grouped quads
  __shared__ u16 xraw[512];        // [2 i][256 s] bf16 bits
  __shared__ float red[4 * 64 * 68]; // [wq][hlocal][f pad 68] cross-wave reduce buf

  const int b = blockIdx.x & 15;
  const int ich = blockIdx.x >> 4;
  const int t = threadIdx.x;

  // ---- stage x (2 rows of 256 fp32 -> bf16) ----
  if (t < 128) {
    int iLoc = t >> 6, s4 = (t & 63) << 2;
    fx4 v = *(const fx4*)(xin + ((b << 5) + (ich << 1) + iLoc) * 256 + s4);
    ux2 p;
    p[0] = pkbf(v[0], v[1]);
    p[1] = pkbf(v[2], v[3]);
    *(ux2*)(xraw + iLoc * 256 + s4) = p;
  }

  // ---- stage kernel slice: 2 i * 64 f * 256 s fp32 -> bf16 LDS, swizzled ----
  // slot = 16B chunk id; swizzle chunk' = chunk ^ (f&31) for conflict-free b128 reads.
#pragma unroll
  for (int it = 0; it < 8; ++it) {
    int slot = it * 512 + t;            // 0..4095
    int iLoc = slot >> 11;
    int f = (slot >> 5) & 63;
    int c = slot & 31;
    int cs = c ^ (f & 31);
    const float* src = kin + f * 8192 + ((ich << 1) + iLoc) * 256 + (cs << 3);
    fx4 v0 = *(const fx4*)src;
    fx4 v1 = *(const fx4*)(src + 4);
    ux4 p;
    p[0] = pkbf(v0[0], v0[1]);
    p[1] = pkbf(v0[2], v0[3]);
    p[2] = pkbf(v1[0], v1[1]);
    p[3] = pkbf(v1[2], v1[3]);
    *(ux4*)(As + slot * 8) = p;
  }
  __syncthreads();

  // ---- build P4: pre-grouped rotation quads, one 16B entry per thread ----
  // entry (iLoc, r, par, u0) holds pairs for u = u0..u0+3:
  //   pair(u) = xr[(c0(u)-par)&15] | xr[(c0(u)-par-1)&15] << 16, c0(u) = (32-2u)&15
  {
    int iLoc = t >> 8, e = t & 255;
    int r = e >> 4, par = (e >> 3) & 1, u0 = e & 7;
    const u16* xr = xraw + iLoc * 256 + (r << 4);
    ux4 q;
#pragma unroll
    for (int j = 0; j < 4; ++j) {
      int u = u0 + j;
      int c0 = (32 - 2 * u) & 15;
      u32 lo = xr[(c0 - par) & 15];
      u32 hi = xr[(c0 - par - 1) & 15];
      q[j] = lo | (hi << 16);
    }
    *(ux4*)(P4 + (t << 2)) = q;
  }
  __syncthreads();

  const int lane = t & 63;
  const int w = t >> 6;
  const int iLoc = w >> 2;
  const int wq = w & 3;
  const int n = lane & 15;
  const int quad = lane >> 4;
  const int s2_0 = (quad & 1) << 3;
  const int par = n & 1;
  const int u0 = ((s2_0 - n - par) & 15) >> 1;
  const int Pb4 = (iLoc << 10) + (par << 5) + (u0 << 2);
  const int s1q = quad >> 1;
  const u16* Aw = As + (iLoc << 14);

  fx4 acc[4][4];
#pragma unroll
  for (int a = 0; a < 4; ++a)
#pragma unroll
    for (int c = 0; c < 4; ++c) acc[a][c] = (fx4){0.f, 0.f, 0.f, 0.f};

#pragma unroll
  for (int kstep = 0; kstep < 8; ++kstep) {
    bfx8 af[4];
#pragma unroll
    for (int ft = 0; ft < 4; ++ft) {
      int f = (ft << 4) + n;
      int ch = ((kstep << 2) + quad) ^ (f & 31);
      af[ft] = *(const bfx8*)(Aw + f * 256 + ch * 8);
    }
    const int s1 = (kstep << 1) + s1q;
    bfx8 bfr[4];
#pragma unroll
    for (int ht = 0; ht < 4; ++ht) {
      int r = ((wq << 2) + ht - s1) & 15;
      bfr[ht] = __builtin_bit_cast(bfx8, *(const ux4*)(P4 + (r << 6) + Pb4));
    }
#pragma unroll
    for (int ft = 0; ft < 4; ++ft)
#pragma unroll
      for (int ht = 0; ht < 4; ++ht)
        acc[ft][ht] =
            __builtin_amdgcn_mfma_f32_16x16x32_bf16(af[ft], bfr[ht], acc[ft][ht], 0, 0, 0);
  }

  // ---- cross-wave (i) reduction: upper waves write, lower add + store ----
  if (w >= 4) {
#pragma unroll
    for (int ft = 0; ft < 4; ++ft)
#pragma unroll
      for (int ht = 0; ht < 4; ++ht) {
        float* pr = &red[wq * 4352 + (ht * 16 + n) * 68 + (ft << 4) + (quad << 2)];
        *(fx4*)pr = acc[ft][ht];
      }
  }
  __syncthreads();
  if (w < 4) {
    float* pw = part + (((ich << 4) + b) << 14);
#pragma unroll
    for (int ft = 0; ft < 4; ++ft)
#pragma unroll
      for (int ht = 0; ht < 4; ++ht) {
        const float* pr = &red[wq * 4352 + (ht * 16 + n) * 68 + (ft << 4) + (quad << 2)];
        fx4 vv = *(const fx4*)pr;
        acc[ft][ht] = acc[ft][ht] + vv;
#pragma unroll
        for (int reg = 0; reg < 4; ++reg) {
          int f = (ft << 4) + (quad << 2) + reg;
          int h = (wq << 6) + (ht << 4) + n;
          pw[f * 256 + h] = acc[ft][ht][reg];
        }
      }
  }
}

// ---------------- split-K reduction + bias ----------------
__global__ __launch_bounds__(256) void eq_reduce(const float* __restrict__ part,
                                                 const float* __restrict__ bias,
                                                 float* __restrict__ out) {
  int o = (blockIdx.x * 256 + threadIdx.x) * 4;
  fx4 s = {0.f, 0.f, 0.f, 0.f};
#pragma unroll
  for (int i = 0; i < 16; ++i) s = s + *(const fx4*)(part + i * 262144 + o);
  float bv = bias[(o >> 8) & 63];
  s = s + (fx4){bv, bv, bv, bv};
  *(fx4*)(out + o) = s;
}

extern "C" void kernel_launch(void* const* d_in, const int* in_sizes, int n_in,
                              void* d_out, int out_size, void* d_ws, size_t ws_size,
                              hipStream_t stream) {
  (void)in_sizes; (void)n_in; (void)out_size; (void)ws_size;
  const float* x = (const float*)d_in[0];
  const float* k = (const float*)d_in[1];
  const float* bias = (const float*)d_in[2];
  // d_in[3] (product_table) unused: translation-group indices computed analytically.
  float* part = (float*)d_ws;   // 16 chunks * 16 b * 64 f * 256 h * 4 B = 16.8 MB
  float* out = (float*)d_out;

  eq_main<<<256, 512, 0, stream>>>(x, k, part);
  eq_reduce<<<256, 256, 0, stream>>>(part, bias, out);
}